// Round 15
// baseline (251.116 us; speedup 1.0000x reference)
//
#include <hip/hip_runtime.h>
#include <hip/hip_bf16.h>

// ---------------------------------------------------------------------------
// HybridFusionNetworkWithUncertainty — MI355X (gfx950), round 15
// r14 passed (229us, intra 127us, 1 blk/CU, 7.4 B/cy path). r15: shrink the
// wide-tile LDS to 72KB -> 2 blocks/CU (DMA burst interleave, r9's proven
// concurrency): B 2x32K (1-ahead, issued BEFORE the counted wait), A single
// 8K buf (safe: commit(t+1) happens after the barrier that ends reads of
// A(t)). FIFO: issue B(t+1)+regs(t+1), vmcnt(6) retires B(t)+regs(t).
// LN epilogue + z^2 pairing + qv/w1/attn/fc/prep = r14 verbatim.
// ws: H [0,64M); zbuf [0,32M); obuf [32M,48M); wb0-3 @64M (intra only);
//     qvout [64M,128M) (stage C clobbers wb*).
// ---------------------------------------------------------------------------

typedef __bf16 bf16;
typedef __bf16 bf16x4_t __attribute__((ext_vector_type(4)));
typedef __bf16 bf16x8_t __attribute__((ext_vector_type(8)));
typedef float  f32x4_t  __attribute__((ext_vector_type(4)));

__device__ __forceinline__ bf16x8_t cvt8(f32x4_t a, f32x4_t b) {
  bf16x8_t r;
  r[0] = (bf16)a[0]; r[1] = (bf16)a[1]; r[2] = (bf16)a[2]; r[3] = (bf16)a[3];
  r[4] = (bf16)b[0]; r[5] = (bf16)b[1]; r[6] = (bf16)b[2]; r[7] = (bf16)b[3];
  return r;
}

__device__ __forceinline__ void gl_lds16(const void* g, void* l) {
  __builtin_amdgcn_global_load_lds(
      (const __attribute__((address_space(1))) void*)g,
      (__attribute__((address_space(3))) void*)l, 16, 0, 0);
}

#define SBAR()   __builtin_amdgcn_s_barrier()
#define SCHED0() __builtin_amdgcn_sched_barrier(0)

// bf16 tile rows of 32 bf16 (64B): chunk c of row r at c^((r>>1)&3)
__device__ __forceinline__ bf16x8_t frag_b16(const bf16* Ts, int row, int c0) {
  const int byte = row * 64 + ((c0 ^ ((row >> 1) & 3)) << 4);
  return *(const bf16x8_t*)((const char*)Ts + byte);
}
// f32 tile rows of 32 f32 (128B): 16B chunk q of row r at q^(r&7)
__device__ __forceinline__ bf16x8_t frag_f32(const float* Ts, int row, int g) {
  const int p0 = (2 * g)     ^ (row & 7);
  const int p1 = (2 * g + 1) ^ (row & 7);
  f32x4_t lo = *(const f32x4_t*)((const char*)Ts + row * 128 + (p0 << 4));
  f32x4_t hi = *(const f32x4_t*)((const char*)Ts + row * 128 + (p1 << 4));
  return cvt8(lo, hi);
}

// ---- 512-thread staging: bf16 [512][32] (32KB), 4 gl_lds/thread ----
__device__ __forceinline__ void stage_b512x32(const bf16* __restrict__ src, int ld,
                                              int k0, bf16* lds) {
  const int l = threadIdx.x & 63;
  const int w = threadIdx.x >> 6;
#pragma unroll
  for (int j = 0; j < 4; ++j) {
    const int rb = w * 64 + j * 16;
    const int r  = rb + (l >> 2);
    const int sc = (l & 3) ^ ((r >> 1) & 3);
    gl_lds16(src + (size_t)r * ld + k0 + sc * 8, (char*)lds + rb * 64);
  }
}

// ---- stage A (fused): intra GEMM 128x512 + relu + LN -> H ----
// LDS 72KB: B buf0 @0 (32K), B buf1 @32768 (32K), A @65536 (8K) -> 2 blk/CU.
__global__ __launch_bounds__(512) void intra_ln_kernel(
    const float* __restrict__ f0, const float* __restrict__ f1,
    const float* __restrict__ f2, const float* __restrict__ f3,
    const bf16* __restrict__ wb0, const bf16* __restrict__ wb1,
    const bf16* __restrict__ wb2, const bf16* __restrict__ wb3,
    const float* __restrict__ bb0, const float* __restrict__ bb1,
    const float* __restrict__ bb2, const float* __restrict__ bb3,
    const float* __restrict__ lng, const float* __restrict__ lnb,
    bf16* __restrict__ Hout) {
  __shared__ __align__(16) char lds[73728];

  const int bid  = blockIdx.x;                     // 512 blocks
  const int p    = bid & 255, half = bid >> 8;
  const int px   = (p & 7) * 32 + (p >> 3);        // XCD-chunked bijection
  int z = px & 3, y = px >> 2;                     // y 0..63
  if (half) { z ^= 2; y += 64; }                   // complementary K pairing
  const float* fp; const bf16* wp; const float* bp; int K;
  switch (z) {
    case 0:  fp = f0; wp = wb0; bp = bb0; K = 1024; break;
    case 1:  fp = f1; wp = wb1; bp = bb1; K = 768;  break;
    case 2:  fp = f2; wp = wb2; bp = bb2; K = 512;  break;
    default: fp = f3; wp = wb3; bp = bb3; K = 640;  break;
  }
  const float* A = fp + (size_t)(y * 128) * K;
  const bf16*  B = wp;
  const int tid = threadIdx.x;
  const int lane = tid & 63;
  const int wid  = tid >> 6;                       // 0..7
  const int wm = wid >> 2, wn = wid & 3;           // wave = 64 rows x 128 cols
  const int fr = lane & 15, g = lane >> 4;

  // A staging geometry: 4 thr/row, 8 f32 each -> one 16B bf16 chunk
  const int srow = tid >> 2, sq = tid & 3;
  const float* Af = A + (size_t)srow * K + sq * 8;
  const int abyte = srow * 64 + ((sq ^ ((srow >> 1) & 3)) << 4);

  f32x4_t acc[4][8];
#pragma unroll
  for (int i = 0; i < 4; ++i)
#pragma unroll
    for (int j = 0; j < 8; ++j) acc[i][j] = (f32x4_t){0.f, 0.f, 0.f, 0.f};

  const int nt = K >> 5;                           // 16..32, always even

  // prologue: B(0) [4 ops], regs(0) [2 ops]  -> outstanding 6
  stage_b512x32(B, K, 0, (bf16*)(lds));
  f32x4_t aA0 = *(const f32x4_t*)(Af + 0);
  f32x4_t aA1 = *(const f32x4_t*)(Af + 4);
  f32x4_t aB0, aB1;

#define INTRA_ITER(T, C0, C1, N0, N1)                                         \
  {                                                                           \
    const int t_ = (T);                                                       \
    if (t_ + 1 < nt) {                                                        \
      stage_b512x32(B, K, (t_ + 1) * 32, (bf16*)(lds + ((t_ + 1) & 1) * 32768)); \
      N0 = *(const f32x4_t*)(Af + (t_ + 1) * 32);                             \
      N1 = *(const f32x4_t*)(Af + (t_ + 1) * 32 + 4);                         \
      asm volatile("s_waitcnt vmcnt(6)" ::: "memory");                        \
    } else {                                                                  \
      asm volatile("s_waitcnt vmcnt(0)" ::: "memory");                        \
    }                                                                         \
    *(bf16x8_t*)(lds + 65536 + abyte) = cvt8(C0, C1);                         \
    asm volatile("s_waitcnt lgkmcnt(0)" ::: "memory");                        \
    SBAR(); SCHED0();                                                         \
    __builtin_amdgcn_s_setprio(1);                                            \
    {                                                                         \
      const bf16* Ac = (const bf16*)(lds + 65536);                            \
      const bf16* Bc = (const bf16*)(lds + (t_ & 1) * 32768);                 \
      bf16x8_t ar[4], br[8];                                                  \
      _Pragma("unroll")                                                       \
      for (int mi = 0; mi < 4; ++mi) ar[mi] = frag_b16(Ac, wm * 64 + mi * 16 + fr, g); \
      _Pragma("unroll")                                                       \
      for (int ni = 0; ni < 8; ++ni) br[ni] = frag_b16(Bc, wn * 128 + ni * 16 + fr, g); \
      _Pragma("unroll")                                                       \
      for (int mi = 0; mi < 4; ++mi)                                          \
        _Pragma("unroll")                                                     \
        for (int ni = 0; ni < 8; ++ni)                                        \
          acc[mi][ni] = __builtin_amdgcn_mfma_f32_16x16x32_bf16(ar[mi], br[ni], acc[mi][ni], 0, 0, 0); \
    }                                                                         \
    __builtin_amdgcn_s_setprio(0);                                            \
    SCHED0(); SBAR();                                                         \
  }

  for (int t = 0; t < nt; t += 2) {
    INTRA_ITER(t,     aA0, aA1, aB0, aB1)
    INTRA_ITER(t + 1, aB0, aB1, aA0, aA1)
  }
#undef INTRA_ITER

  // ---- fused LayerNorm epilogue (r12-proven) ----
  float* part  = (float*)lds;                      // [8][64][2] = 4KB
  float* muinv = (float*)(lds + 4096);             // [128][2]   = 1KB
  float bv8[8];
#pragma unroll
  for (int ni = 0; ni < 8; ++ni) bv8[ni] = bp[wn * 128 + ni * 16 + fr];
#pragma unroll
  for (int mi = 0; mi < 4; ++mi)
#pragma unroll
    for (int j = 0; j < 4; ++j) {
      float s = 0.f, s2 = 0.f;
#pragma unroll
      for (int ni = 0; ni < 8; ++ni) {
        float v = fmaxf(acc[mi][ni][j] + bv8[ni], 0.f);
        s += v; s2 += v * v;
      }
#pragma unroll
      for (int off = 1; off < 16; off <<= 1) {
        s += __shfl_xor(s, off); s2 += __shfl_xor(s2, off);
      }
      if (fr == 0) {
        const int rl = mi * 16 + 4 * g + j;        // 0..63
        part[(wid * 64 + rl) * 2]     = s;
        part[(wid * 64 + rl) * 2 + 1] = s2;
      }
    }
  __syncthreads();
  if (tid < 128) {
    const int wmt = tid >> 6, rl = tid & 63;
    float s = 0.f, s2 = 0.f;
#pragma unroll
    for (int q = 0; q < 4; ++q) {
      s  += part[((wmt * 4 + q) * 64 + rl) * 2];
      s2 += part[((wmt * 4 + q) * 64 + rl) * 2 + 1];
    }
    const float mu  = s * (1.f / 512.f);
    const float var = s2 * (1.f / 512.f) - mu * mu;
    muinv[tid * 2]     = mu;
    muinv[tid * 2 + 1] = rsqrtf(var + 1e-5f);
  }
  __syncthreads();
  float gg[8], be[8];
#pragma unroll
  for (int ni = 0; ni < 8; ++ni) {
    const int col = wn * 128 + ni * 16 + fr;
    gg[ni] = lng[col]; be[ni] = lnb[col];
  }
#pragma unroll
  for (int mi = 0; mi < 4; ++mi)
#pragma unroll
    for (int j = 0; j < 4; ++j) {
      const int row = wm * 64 + mi * 16 + 4 * g + j;
      const float mu  = muinv[row * 2];
      const float inv = muinv[row * 2 + 1];
      bf16* hp = Hout + (size_t)(y * 128 + row) * 2048 + z * 512;
#pragma unroll
      for (int ni = 0; ni < 8; ++ni) {
        float v = fmaxf(acc[mi][ni][j] + bv8[ni], 0.f);
        hp[wn * 128 + ni * 16 + fr] = (bf16)((v - mu) * inv * gg[ni] + be[ni]);
      }
    }
}

// ================= 256-thread helpers (qv/w1, r12-verified) =================
__device__ __forceinline__ void stage_b16(const bf16* __restrict__ src, int ld,
                                          int k0, bf16* lds) {
  const int l = threadIdx.x & 63;
  const int w = threadIdx.x >> 6;
#pragma unroll
  for (int j = 0; j < 2; ++j) {
    const int rb = w * 32 + j * 16;
    const int r  = rb + (l >> 2);
    const int sc = (l & 3) ^ ((r >> 1) & 3);
    gl_lds16(src + (size_t)r * ld + k0 + sc * 8, (char*)lds + rb * 64);
  }
}
__device__ __forceinline__ void stage_f32(const float* __restrict__ src, int ld,
                                          int k0, float* lds) {
  const int l = threadIdx.x & 63;
  const int w = threadIdx.x >> 6;
#pragma unroll
  for (int j = 0; j < 4; ++j) {
    const int rb = w * 32 + j * 8;
    const int r  = rb + (l >> 3);
    const int q  = (l & 7) ^ (r & 7);
    gl_lds16(src + (size_t)r * ld + k0 + q * 4, (char*)lds + rb * 128);
  }
}
__device__ __forceinline__ void mfma_deep0(const char* buf, f32x4_t acc[4][4]) {
  const int lane = threadIdx.x & 63;
  const int wid  = threadIdx.x >> 6;
  const int wm = wid >> 1, wn = wid & 1;
  const int fr = lane & 15, g = lane >> 4;
  const bf16*  Ab = (const bf16*)buf;
  const float* Bf = (const float*)(buf + 8192);
  bf16x8_t ar[4], br[4];
#pragma unroll
  for (int mi = 0; mi < 4; ++mi) ar[mi] = frag_b16(Ab, wm * 64 + mi * 16 + fr, g);
#pragma unroll
  for (int ni = 0; ni < 4; ++ni) br[ni] = frag_f32(Bf, wn * 64 + ni * 16 + fr, g);
#pragma unroll
  for (int mi = 0; mi < 4; ++mi)
#pragma unroll
    for (int ni = 0; ni < 4; ++ni)
      acc[mi][ni] = __builtin_amdgcn_mfma_f32_16x16x32_bf16(ar[mi], br[ni], acc[mi][ni], 0, 0, 0);
}
__device__ __forceinline__ void core_deep3_0(const void* A, int lda, const void* B,
                                             int ldb, int K, char* lds,
                                             f32x4_t acc[4][4]) {
  const int nt = K >> 5;
  auto stage = [&](int t, char* buf) {
    stage_b16((const bf16*)A, lda, t * 32, (bf16*)buf);
    stage_f32((const float*)B, ldb, t * 32, (float*)(buf + 8192));
  };
  stage(0, lds); stage(1, lds + 24576); stage(2, lds + 49152);
  int bsel = 0;
  for (int t = 0; t < nt; ++t) {
    const int ahead = nt - 1 - t;
    if (ahead >= 2)      asm volatile("s_waitcnt vmcnt(12)" ::: "memory");
    else if (ahead == 1) asm volatile("s_waitcnt vmcnt(6)"  ::: "memory");
    else                 asm volatile("s_waitcnt vmcnt(0)"  ::: "memory");
    SBAR(); SCHED0();
    __builtin_amdgcn_s_setprio(1);
    mfma_deep0(lds + bsel * 24576, acc);
    __builtin_amdgcn_s_setprio(0);
    SCHED0(); SBAR();
    if (t + 3 < nt) stage(t + 3, lds + bsel * 24576);
    bsel = (bsel == 2) ? 0 : bsel + 1;
  }
}
template<int RELU>
__device__ __forceinline__ void epi_bf16(f32x4_t acc[4][4], bf16* __restrict__ C, int ldc,
                                         const float* __restrict__ bias) {
  const int lane = threadIdx.x & 63;
  const int wid  = threadIdx.x >> 6;
  const int wm = wid >> 1, wn = wid & 1;
  const int fr = lane & 15;
  const int rb = wm * 64 + 4 * (lane >> 4);
  const int cb = wn * 64 + fr;
  float bv[4];
#pragma unroll
  for (int ni = 0; ni < 4; ++ni) bv[ni] = bias[cb + ni * 16];
#pragma unroll
  for (int mi = 0; mi < 4; ++mi)
#pragma unroll
    for (int j = 0; j < 4; ++j)
#pragma unroll
      for (int ni = 0; ni < 4; ++ni) {
        float val = acc[mi][ni][j] + bv[ni];
        if (RELU) val = fmaxf(val, 0.f);
        C[(size_t)(rb + mi * 16 + j) * ldc + cb + ni * 16] = (bf16)val;
      }
}

// ---- stage C: fused q||v projection (65536 x 256 each, K=512) ----
__global__ __launch_bounds__(256) void qv_kernel(
    const bf16* __restrict__ H, const float* __restrict__ Wq,
    const float* __restrict__ Wv, const float* __restrict__ bq,
    const float* __restrict__ bv, bf16* __restrict__ qvout) {
  __shared__ __align__(16) char lds[73728];
  const int bid = blockIdx.x;                     // 2048 blocks
  const int lid = (bid & 7) * 256 + (bid >> 3);
  const int x = lid & 3, y = lid >> 2;            // y: 0..511
  const float* Wsrc = (x < 2) ? Wq : Wv;
  f32x4_t acc[4][4];
#pragma unroll
  for (int i = 0; i < 4; ++i)
#pragma unroll
    for (int j = 0; j < 4; ++j) acc[i][j] = (f32x4_t){0.f, 0.f, 0.f, 0.f};
  core_deep3_0(H + (size_t)(y * 128) * 512, 512,
               Wsrc + (size_t)((x & 1) * 128) * 512, 512, 512, lds, acc);
  const float* bias = (x < 2) ? bq + x * 128 : bv + (x - 2) * 128;
  epi_bf16<0>(acc, qvout + (size_t)(y * 128) * 512 + x * 128, 512, bias);
}

// ---- stage E: W1 GEMM (K=1024, ldw=1028) + pred_scores rank-4 fixup ----
__global__ __launch_bounds__(256) void w1_kernel(
    const bf16* __restrict__ zb, const float* __restrict__ W1,
    const float* __restrict__ b1, const float* __restrict__ ps,
    float* __restrict__ obuf) {
  __shared__ __align__(16) char lds[73728];
  const int bid = blockIdx.x;                     // 256 blocks
  const int lid = (bid & 7) * 32 + (bid >> 3);
  const int x = lid & 1, y = lid >> 1;            // y: 0..127
  f32x4_t acc[4][4];
#pragma unroll
  for (int i = 0; i < 4; ++i)
#pragma unroll
    for (int j = 0; j < 4; ++j) acc[i][j] = (f32x4_t){0.f, 0.f, 0.f, 0.f};
  core_deep3_0(zb + (size_t)(y * 128) * 1024, 1024,
               W1 + (size_t)(x * 128) * 1028, 1028, 1024, lds, acc);

  const int lane = threadIdx.x & 63;
  const int wid  = threadIdx.x >> 6;
  const int wm = wid >> 1, wn = wid & 1;
  const int fr = lane & 15;
  const int rb = wm * 64 + 4 * (lane >> 4);
  const int cb = x * 128 + wn * 64 + fr;
  float bv[4], wt[4][4];
#pragma unroll
  for (int ni = 0; ni < 4; ++ni) {
    bv[ni] = b1[cb + ni * 16];
#pragma unroll
    for (int m = 0; m < 4; ++m) wt[ni][m] = W1[(size_t)(cb + ni * 16) * 1028 + 1024 + m];
  }
#pragma unroll
  for (int mi = 0; mi < 4; ++mi)
#pragma unroll
    for (int j = 0; j < 4; ++j) {
      const int r = y * 128 + rb + mi * 16 + j;
      f32x4_t psv = *(const f32x4_t*)(ps + (size_t)r * 4);
#pragma unroll
      for (int ni = 0; ni < 4; ++ni) {
        float val = acc[mi][ni][j] + bv[ni]
                  + psv[0] * wt[ni][0] + psv[1] * wt[ni][1]
                  + psv[2] * wt[ni][2] + psv[3] * wt[ni][3];
        obuf[(size_t)r * 256 + cb + ni * 16] = val;
      }
    }
}

// ---- prep: convert intra weights f32 -> bf16 ----
__device__ __forceinline__ void cp8(bf16* d, const float* s) {
  f32x4_t x0 = *(const f32x4_t*)s;
  f32x4_t x1 = *(const f32x4_t*)(s + 4);
  *(bf16x8_t*)d = cvt8(x0, x1);
}
__global__ __launch_bounds__(256) void prep_kernel(
    const float* __restrict__ w0, const float* __restrict__ w1s,
    const float* __restrict__ w2, const float* __restrict__ w3,
    bf16* __restrict__ o0, bf16* __restrict__ o1,
    bf16* __restrict__ o2, bf16* __restrict__ o3) {
  const int t = blockIdx.x * 256 + threadIdx.x;
  if (t < 65536)       { size_t i = (size_t)t * 8;            cp8(o0 + i, w0 + i); }
  else if (t < 114688) { size_t i = (size_t)(t - 65536) * 8;  cp8(o1 + i, w1s + i); }
  else if (t < 147456) { size_t i = (size_t)(t - 114688) * 8; cp8(o2 + i, w2 + i); }
  else                 { size_t i = (size_t)(t - 147456) * 8; cp8(o3 + i, w3 + i); }
}

// ---- attention: 4x4 scores (k=q per source bug), softmax(-UW*(vi+vj)), z=s@v ----
__global__ __launch_bounds__(256)
void attn_kernel(const bf16* __restrict__ qv, const float* __restrict__ pvars,
                 bf16* __restrict__ z) {
  const int b    = blockIdx.x * 4 + (threadIdx.x >> 6);
  const int lane = threadIdx.x & 63;
  float qf[4][4], vf[4][4];
#pragma unroll
  for (int i = 0; i < 4; ++i) {
    const bf16* row = qv + ((size_t)b * 4 + i) * 512;
    bf16x4_t qq = *(const bf16x4_t*)(row + lane * 4);
    bf16x4_t vv = *(const bf16x4_t*)(row + 256 + lane * 4);
#pragma unroll
    for (int c = 0; c < 4; ++c) { qf[i][c] = (float)qq[c]; vf[i][c] = (float)vv[c]; }
  }
  float s[4][4];
#pragma unroll
  for (int i = 0; i < 4; ++i)
#pragma unroll
    for (int j = 0; j < 4; ++j)
      s[i][j] = qf[i][0] * qf[j][0] + qf[i][1] * qf[j][1] + qf[i][2] * qf[j][2] + qf[i][3] * qf[j][3];
#pragma unroll
  for (int off = 1; off < 64; off <<= 1)
#pragma unroll
    for (int i = 0; i < 4; ++i)
#pragma unroll
      for (int j = 0; j < 4; ++j) s[i][j] += __shfl_xor(s[i][j], off);

  float var4[4];
#pragma unroll
  for (int m = 0; m < 4; ++m) var4[m] = pvars[(size_t)b * 4 + m];
  float w[4][4];
#pragma unroll
  for (int i = 0; i < 4; ++i) {
    float t[4]; float mx = -1e30f;
#pragma unroll
    for (int j = 0; j < 4; ++j) { t[j] = s[i][j] - 0.1f * (var4[i] + var4[j]); mx = fmaxf(mx, t[j]); }
    float sum = 0.f;
#pragma unroll
    for (int j = 0; j < 4; ++j) { t[j] = expf(t[j] - mx); sum += t[j]; }
    const float is = 1.f / sum;
#pragma unroll
    for (int j = 0; j < 4; ++j) w[i][j] = t[j] * is;
  }
#pragma unroll
  for (int i = 0; i < 4; ++i) {
    bf16x4_t zo;
#pragma unroll
    for (int c = 0; c < 4; ++c) {
      float zf = w[i][0] * vf[0][c] + w[i][1] * vf[1][c] + w[i][2] * vf[2][c] + w[i][3] * vf[3][c];
      zo[c] = (bf16)zf;
    }
    *(bf16x4_t*)(z + ((size_t)b * 4 + i) * 256 + lane * 4) = zo;
  }
}

// ---- final fc (256 -> 1) + sigmoid ----
__global__ __launch_bounds__(256)
void fc_kernel(const float* __restrict__ o, const float* __restrict__ wfc,
               const float* __restrict__ bfc, float* __restrict__ out) {
  const int b    = blockIdx.x * 4 + (threadIdx.x >> 6);
  const int lane = threadIdx.x & 63;
  f32x4_t ov = *(const f32x4_t*)(o + (size_t)b * 256 + lane * 4);
  f32x4_t wv = *(const f32x4_t*)(wfc + lane * 4);
  float p = ov[0] * wv[0] + ov[1] * wv[1] + ov[2] * wv[2] + ov[3] * wv[3];
#pragma unroll
  for (int off = 1; off < 64; off <<= 1) p += __shfl_xor(p, off);
  if (lane == 0) {
    const float lg = p + bfc[0];
    out[b] = 1.f / (1.f + expf(-lg));
  }
}

extern "C" void kernel_launch(void* const* d_in, const int* in_sizes, int n_in,
                              void* d_out, int out_size, void* d_ws, size_t ws_size,
                              hipStream_t stream) {
  (void)in_sizes; (void)n_in; (void)out_size; (void)ws_size;
  const float* feat[4] = {(const float*)d_in[0], (const float*)d_in[3],
                          (const float*)d_in[6], (const float*)d_in[9]};
  const float* Wi[4]   = {(const float*)d_in[1], (const float*)d_in[4],
                          (const float*)d_in[7], (const float*)d_in[10]};
  const float* bi[4]   = {(const float*)d_in[2], (const float*)d_in[5],
                          (const float*)d_in[8], (const float*)d_in[11]};
  const float* ps  = (const float*)d_in[12];
  const float* pv  = (const float*)d_in[13];
  const float* lng = (const float*)d_in[14];
  const float* lnb = (const float*)d_in[15];
  const float* Wq  = (const float*)d_in[16];
  const float* bq  = (const float*)d_in[17];
  const float* Wv  = (const float*)d_in[20];
  const float* bvp = (const float*)d_in[21];
  const float* W1  = (const float*)d_in[22];
  const float* b1  = (const float*)d_in[23];
  const float* Wfc = (const float*)d_in[24];
  const float* bfc = (const float*)d_in[25];

  char* ws = (char*)d_ws;
  const size_t MB = 1024 * 1024;
  bf16*  hbuf  = (bf16*)ws;                        // [0,64M): H (intra_ln out)
  bf16*  zbuf  = (bf16*)ws;                        // [0,32M): z (after stage C)
  float* obuf  = (float*)(ws + 32 * MB);           // [32M,48M)
  bf16*  wb0   = (bf16*)(ws + 64 * MB);            // intra only
  bf16*  wb1   = (bf16*)(ws + 65 * MB);
  bf16*  wb2   = (bf16*)(ws + 65 * MB + 786432);
  bf16*  wb3   = (bf16*)(ws + 66 * MB + 262144);
  bf16*  qvout = (bf16*)(ws + 64 * MB);            // stage C (clobbers wb*)

  hipLaunchKernelGGL(prep_kernel, dim3(736), dim3(256), 0, stream,
                     Wi[0], Wi[1], Wi[2], Wi[3], wb0, wb1, wb2, wb3);
  hipLaunchKernelGGL(intra_ln_kernel, dim3(512), dim3(512), 0, stream,
                     feat[0], feat[1], feat[2], feat[3],
                     wb0, wb1, wb2, wb3, bi[0], bi[1], bi[2], bi[3],
                     lng, lnb, hbuf);
  hipLaunchKernelGGL(qv_kernel, dim3(2048), dim3(256), 0, stream,
                     hbuf, Wq, Wv, bq, bvp, qvout);
  hipLaunchKernelGGL(attn_kernel, dim3(16384 / 4), dim3(256), 0, stream, qvout, pv, zbuf);
  hipLaunchKernelGGL(w1_kernel, dim3(256), dim3(256), 0, stream, zbuf, W1, b1, ps, obuf);
  hipLaunchKernelGGL(fc_kernel, dim3(16384 / 4), dim3(256), 0, stream, obuf, Wfc, bfc, (float*)d_out);
}

// Round 17
// 248.136 us; speedup vs baseline: 1.0120x; 1.0120x over previous
//
#include <hip/hip_runtime.h>
#include <hip/hip_bf16.h>

// ---------------------------------------------------------------------------
// HybridFusionNetworkWithUncertainty — MI355X (gfx950), round 17
// r16 bug: grid=256 but work=512 tiles (y only reached 63 -> half of H
// stale -> absmax 0.47). Fix: grid=512 with r14's balanced mapping
// (p&255 XCD bijection; half: z^=2, y+=64). Kernel bodies = r16 verbatim:
// 1024-thr block (16 waves, 64x64 each), all-gl_lds, A 2-buf(1-ahead) +
// B 3-buf(2-ahead), vmcnt(5/3/0), 128KB LDS, fused LN epilogue (2x8 grid).
// qv/w1/attn/fc/prep = r14 verbatim (passing).
// ws: H [0,64M); zbuf [0,32M); obuf [32M,48M); wb0-3 @64M (intra only);
//     qvout [64M,128M) (stage C clobbers wb*).
// ---------------------------------------------------------------------------

typedef __bf16 bf16;
typedef __bf16 bf16x4_t __attribute__((ext_vector_type(4)));
typedef __bf16 bf16x8_t __attribute__((ext_vector_type(8)));
typedef float  f32x4_t  __attribute__((ext_vector_type(4)));

__device__ __forceinline__ bf16x8_t cvt8(f32x4_t a, f32x4_t b) {
  bf16x8_t r;
  r[0] = (bf16)a[0]; r[1] = (bf16)a[1]; r[2] = (bf16)a[2]; r[3] = (bf16)a[3];
  r[4] = (bf16)b[0]; r[5] = (bf16)b[1]; r[6] = (bf16)b[2]; r[7] = (bf16)b[3];
  return r;
}

__device__ __forceinline__ void gl_lds16(const void* g, void* l) {
  __builtin_amdgcn_global_load_lds(
      (const __attribute__((address_space(1))) void*)g,
      (__attribute__((address_space(3))) void*)l, 16, 0, 0);
}

#define SBAR()   __builtin_amdgcn_s_barrier()
#define SCHED0() __builtin_amdgcn_sched_barrier(0)

// bf16 tile rows of 32 bf16 (64B): chunk c of row r at c^((r>>1)&3)
__device__ __forceinline__ bf16x8_t frag_b16(const bf16* Ts, int row, int c0) {
  const int byte = row * 64 + ((c0 ^ ((row >> 1) & 3)) << 4);
  return *(const bf16x8_t*)((const char*)Ts + byte);
}
// f32 tile rows of 32 f32 (128B): 16B chunk q of row r at q^(r&7)
__device__ __forceinline__ bf16x8_t frag_f32(const float* Ts, int row, int g) {
  const int p0 = (2 * g)     ^ (row & 7);
  const int p1 = (2 * g + 1) ^ (row & 7);
  f32x4_t lo = *(const f32x4_t*)((const char*)Ts + row * 128 + (p0 << 4));
  f32x4_t hi = *(const f32x4_t*)((const char*)Ts + row * 128 + (p1 << 4));
  return cvt8(lo, hi);
}

// ---- stage A (fused): intra GEMM 128x512 + relu + LN -> H ; 1024 threads ----
__global__ __launch_bounds__(1024, 4) void intra_ln_kernel(
    const float* __restrict__ f0, const float* __restrict__ f1,
    const float* __restrict__ f2, const float* __restrict__ f3,
    const bf16* __restrict__ wb0, const bf16* __restrict__ wb1,
    const bf16* __restrict__ wb2, const bf16* __restrict__ wb3,
    const float* __restrict__ bb0, const float* __restrict__ bb1,
    const float* __restrict__ bb2, const float* __restrict__ bb3,
    const float* __restrict__ lng, const float* __restrict__ lnb,
    bf16* __restrict__ Hout) {
  __shared__ __align__(16) char lds[131072];       // B 3x32K @0 + A 2x16K @98304

  const int bid  = blockIdx.x;                     // 512 blocks
  const int p    = bid & 255, half = bid >> 8;
  const int px   = (p & 7) * 32 + (p >> 3);        // XCD-chunked bijection
  int z = px & 3, y = px >> 2;                     // y 0..63
  if (half) { z ^= 2; y += 64; }                   // complementary K pairing
  const float* fp; const bf16* wp; const float* bp; int K;
  switch (z) {
    case 0:  fp = f0; wp = wb0; bp = bb0; K = 1024; break;
    case 1:  fp = f1; wp = wb1; bp = bb1; K = 768;  break;
    case 2:  fp = f2; wp = wb2; bp = bb2; K = 512;  break;
    default: fp = f3; wp = wb3; bp = bb3; K = 640;  break;
  }
  const float* A = fp + (size_t)(y * 128) * K;
  const bf16*  B = wp;
  const int tid  = threadIdx.x;
  const int lane = tid & 63;
  const int wid  = tid >> 6;                       // 0..15
  const int wm = wid >> 3, wn = wid & 7;           // wave = 64 rows x 64 cols
  const int fr = lane & 15, g = lane >> 4;

  f32x4_t acc[4][4];
#pragma unroll
  for (int i = 0; i < 4; ++i)
#pragma unroll
    for (int j = 0; j < 4; ++j) acc[i][j] = (f32x4_t){0.f, 0.f, 0.f, 0.f};

  const int nt = K >> 5;                           // 16..32

  // A f32 [128][32] (16KB/buf): 1 gl_lds/thread; wave w covers rows w*8..+8
  auto stageA = [&](int t) {
    const int rb = wid * 8;
    const int r  = rb + (lane >> 3);
    const int q  = (lane & 7) ^ (r & 7);
    gl_lds16(A + (size_t)r * K + t * 32 + q * 4,
             lds + 98304 + (t & 1) * 16384 + rb * 128);
  };
  // B bf16 [512][32] (32KB/buf): 2 gl_lds/thread; wave w covers rows w*32..+32
  auto stageB = [&](int t) {
#pragma unroll
    for (int j = 0; j < 2; ++j) {
      const int rb = wid * 32 + j * 16;
      const int r  = rb + (lane >> 2);
      const int sc = (lane & 3) ^ ((r >> 1) & 3);
      gl_lds16(B + (size_t)r * K + t * 32 + sc * 8,
               lds + (t % 3) * 32768 + rb * 64);
    }
  };

  stageA(0); stageB(0); stageB(1);                 // outstanding 5
  for (int t = 0; t < nt; ++t) {
    if (t + 1 < nt) stageA(t + 1);
    if (t + 2 < nt) stageB(t + 2);
    const int rem = ((t + 1 < nt) ? 3 : 0) + ((t + 2 < nt) ? 2 : 0);
    if (rem == 5)      asm volatile("s_waitcnt vmcnt(5)" ::: "memory");
    else if (rem == 3) asm volatile("s_waitcnt vmcnt(3)" ::: "memory");
    else               asm volatile("s_waitcnt vmcnt(0)" ::: "memory");
    SBAR(); SCHED0();
    __builtin_amdgcn_s_setprio(1);
    {
      const float* Ac = (const float*)(lds + 98304 + (t & 1) * 16384);
      const bf16*  Bc = (const bf16*)(lds + (t % 3) * 32768);
      bf16x8_t ar[4], br[4];
#pragma unroll
      for (int mi = 0; mi < 4; ++mi) ar[mi] = frag_f32(Ac, wm * 64 + mi * 16 + fr, g);
#pragma unroll
      for (int ni = 0; ni < 4; ++ni) br[ni] = frag_b16(Bc, wn * 64 + ni * 16 + fr, g);
#pragma unroll
      for (int mi = 0; mi < 4; ++mi)
#pragma unroll
        for (int ni = 0; ni < 4; ++ni)
          acc[mi][ni] = __builtin_amdgcn_mfma_f32_16x16x32_bf16(ar[mi], br[ni], acc[mi][ni], 0, 0, 0);
    }
    __builtin_amdgcn_s_setprio(0);
    SCHED0(); SBAR();
  }

  // ---- fused LayerNorm epilogue (2x8 wave grid) ----
  float* part  = (float*)lds;                      // [16][64][2] = 8KB
  float* muinv = (float*)(lds + 8192);             // [128][2]    = 1KB
  float bv4[4];
#pragma unroll
  for (int ni = 0; ni < 4; ++ni) bv4[ni] = bp[wn * 64 + ni * 16 + fr];
#pragma unroll
  for (int mi = 0; mi < 4; ++mi)
#pragma unroll
    for (int j = 0; j < 4; ++j) {
      float s = 0.f, s2 = 0.f;
#pragma unroll
      for (int ni = 0; ni < 4; ++ni) {
        float v = fmaxf(acc[mi][ni][j] + bv4[ni], 0.f);
        s += v; s2 += v * v;
      }
#pragma unroll
      for (int off = 1; off < 16; off <<= 1) {
        s += __shfl_xor(s, off); s2 += __shfl_xor(s2, off);
      }
      if (fr == 0) {
        const int rl = mi * 16 + 4 * g + j;        // 0..63 (wave-local row)
        part[(wid * 64 + rl) * 2]     = s;
        part[(wid * 64 + rl) * 2 + 1] = s2;
      }
    }
  __syncthreads();
  if (tid < 128) {
    const int wmt = tid >> 6, rl = tid & 63;       // global row = tid
    float s = 0.f, s2 = 0.f;
#pragma unroll
    for (int q = 0; q < 8; ++q) {                  // 8 wn-waves share the row
      s  += part[((wmt * 8 + q) * 64 + rl) * 2];
      s2 += part[((wmt * 8 + q) * 64 + rl) * 2 + 1];
    }
    const float mu  = s * (1.f / 512.f);
    const float var = s2 * (1.f / 512.f) - mu * mu;
    muinv[tid * 2]     = mu;
    muinv[tid * 2 + 1] = rsqrtf(var + 1e-5f);
  }
  __syncthreads();
  float gg[4], be[4];
#pragma unroll
  for (int ni = 0; ni < 4; ++ni) {
    const int col = wn * 64 + ni * 16 + fr;
    gg[ni] = lng[col]; be[ni] = lnb[col];
  }
#pragma unroll
  for (int mi = 0; mi < 4; ++mi)
#pragma unroll
    for (int j = 0; j < 4; ++j) {
      const int row = wm * 64 + mi * 16 + 4 * g + j;
      const float mu  = muinv[row * 2];
      const float inv = muinv[row * 2 + 1];
      bf16* hp = Hout + (size_t)(y * 128 + row) * 2048 + z * 512;
#pragma unroll
      for (int ni = 0; ni < 4; ++ni) {
        float v = fmaxf(acc[mi][ni][j] + bv4[ni], 0.f);
        hp[wn * 64 + ni * 16 + fr] = (bf16)((v - mu) * inv * gg[ni] + be[ni]);
      }
    }
}

// ================= 256-thread helpers (qv/w1, r12/r14-verified) =================
__device__ __forceinline__ void stage_b16(const bf16* __restrict__ src, int ld,
                                          int k0, bf16* lds) {
  const int l = threadIdx.x & 63;
  const int w = threadIdx.x >> 6;
#pragma unroll
  for (int j = 0; j < 2; ++j) {
    const int rb = w * 32 + j * 16;
    const int r  = rb + (l >> 2);
    const int sc = (l & 3) ^ ((r >> 1) & 3);
    gl_lds16(src + (size_t)r * ld + k0 + sc * 8, (char*)lds + rb * 64);
  }
}
__device__ __forceinline__ void stage_f32(const float* __restrict__ src, int ld,
                                          int k0, float* lds) {
  const int l = threadIdx.x & 63;
  const int w = threadIdx.x >> 6;
#pragma unroll
  for (int j = 0; j < 4; ++j) {
    const int rb = w * 32 + j * 8;
    const int r  = rb + (l >> 3);
    const int q  = (l & 7) ^ (r & 7);
    gl_lds16(src + (size_t)r * ld + k0 + q * 4, (char*)lds + rb * 128);
  }
}
__device__ __forceinline__ void mfma_deep0(const char* buf, f32x4_t acc[4][4]) {
  const int lane = threadIdx.x & 63;
  const int wid  = threadIdx.x >> 6;
  const int wm = wid >> 1, wn = wid & 1;
  const int fr = lane & 15, g = lane >> 4;
  const bf16*  Ab = (const bf16*)buf;
  const float* Bf = (const float*)(buf + 8192);
  bf16x8_t ar[4], br[4];
#pragma unroll
  for (int mi = 0; mi < 4; ++mi) ar[mi] = frag_b16(Ab, wm * 64 + mi * 16 + fr, g);
#pragma unroll
  for (int ni = 0; ni < 4; ++ni) br[ni] = frag_f32(Bf, wn * 64 + ni * 16 + fr, g);
#pragma unroll
  for (int mi = 0; mi < 4; ++mi)
#pragma unroll
    for (int ni = 0; ni < 4; ++ni)
      acc[mi][ni] = __builtin_amdgcn_mfma_f32_16x16x32_bf16(ar[mi], br[ni], acc[mi][ni], 0, 0, 0);
}
__device__ __forceinline__ void core_deep3_0(const void* A, int lda, const void* B,
                                             int ldb, int K, char* lds,
                                             f32x4_t acc[4][4]) {
  const int nt = K >> 5;
  auto stage = [&](int t, char* buf) {
    stage_b16((const bf16*)A, lda, t * 32, (bf16*)buf);
    stage_f32((const float*)B, ldb, t * 32, (float*)(buf + 8192));
  };
  stage(0, lds); stage(1, lds + 24576); stage(2, lds + 49152);
  int bsel = 0;
  for (int t = 0; t < nt; ++t) {
    const int ahead = nt - 1 - t;
    if (ahead >= 2)      asm volatile("s_waitcnt vmcnt(12)" ::: "memory");
    else if (ahead == 1) asm volatile("s_waitcnt vmcnt(6)"  ::: "memory");
    else                 asm volatile("s_waitcnt vmcnt(0)"  ::: "memory");
    SBAR(); SCHED0();
    __builtin_amdgcn_s_setprio(1);
    mfma_deep0(lds + bsel * 24576, acc);
    __builtin_amdgcn_s_setprio(0);
    SCHED0(); SBAR();
    if (t + 3 < nt) stage(t + 3, lds + bsel * 24576);
    bsel = (bsel == 2) ? 0 : bsel + 1;
  }
}
template<int RELU>
__device__ __forceinline__ void epi_bf16(f32x4_t acc[4][4], bf16* __restrict__ C, int ldc,
                                         const float* __restrict__ bias) {
  const int lane = threadIdx.x & 63;
  const int wid  = threadIdx.x >> 6;
  const int wm = wid >> 1, wn = wid & 1;
  const int fr = lane & 15;
  const int rb = wm * 64 + 4 * (lane >> 4);
  const int cb = wn * 64 + fr;
  float bv[4];
#pragma unroll
  for (int ni = 0; ni < 4; ++ni) bv[ni] = bias[cb + ni * 16];
#pragma unroll
  for (int mi = 0; mi < 4; ++mi)
#pragma unroll
    for (int j = 0; j < 4; ++j)
#pragma unroll
      for (int ni = 0; ni < 4; ++ni) {
        float val = acc[mi][ni][j] + bv[ni];
        if (RELU) val = fmaxf(val, 0.f);
        C[(size_t)(rb + mi * 16 + j) * ldc + cb + ni * 16] = (bf16)val;
      }
}

// ---- stage C: fused q||v projection (65536 x 256 each, K=512) ----
__global__ __launch_bounds__(256) void qv_kernel(
    const bf16* __restrict__ H, const float* __restrict__ Wq,
    const float* __restrict__ Wv, const float* __restrict__ bq,
    const float* __restrict__ bv, bf16* __restrict__ qvout) {
  __shared__ __align__(16) char lds[73728];
  const int bid = blockIdx.x;                     // 2048 blocks
  const int lid = (bid & 7) * 256 + (bid >> 3);
  const int x = lid & 3, y = lid >> 2;            // y: 0..511
  const float* Wsrc = (x < 2) ? Wq : Wv;
  f32x4_t acc[4][4];
#pragma unroll
  for (int i = 0; i < 4; ++i)
#pragma unroll
    for (int j = 0; j < 4; ++j) acc[i][j] = (f32x4_t){0.f, 0.f, 0.f, 0.f};
  core_deep3_0(H + (size_t)(y * 128) * 512, 512,
               Wsrc + (size_t)((x & 1) * 128) * 512, 512, 512, lds, acc);
  const float* bias = (x < 2) ? bq + x * 128 : bv + (x - 2) * 128;
  epi_bf16<0>(acc, qvout + (size_t)(y * 128) * 512 + x * 128, 512, bias);
}

// ---- stage E: W1 GEMM (K=1024, ldw=1028) + pred_scores rank-4 fixup ----
__global__ __launch_bounds__(256) void w1_kernel(
    const bf16* __restrict__ zb, const float* __restrict__ W1,
    const float* __restrict__ b1, const float* __restrict__ ps,
    float* __restrict__ obuf) {
  __shared__ __align__(16) char lds[73728];
  const int bid = blockIdx.x;                     // 256 blocks
  const int lid = (bid & 7) * 32 + (bid >> 3);
  const int x = lid & 1, y = lid >> 1;            // y: 0..127
  f32x4_t acc[4][4];
#pragma unroll
  for (int i = 0; i < 4; ++i)
#pragma unroll
    for (int j = 0; j < 4; ++j) acc[i][j] = (f32x4_t){0.f, 0.f, 0.f, 0.f};
  core_deep3_0(zb + (size_t)(y * 128) * 1024, 1024,
               W1 + (size_t)(x * 128) * 1028, 1028, 1024, lds, acc);

  const int lane = threadIdx.x & 63;
  const int wid  = threadIdx.x >> 6;
  const int wm = wid >> 1, wn = wid & 1;
  const int fr = lane & 15;
  const int rb = wm * 64 + 4 * (lane >> 4);
  const int cb = x * 128 + wn * 64 + fr;
  float bv[4], wt[4][4];
#pragma unroll
  for (int ni = 0; ni < 4; ++ni) {
    bv[ni] = b1[cb + ni * 16];
#pragma unroll
    for (int m = 0; m < 4; ++m) wt[ni][m] = W1[(size_t)(cb + ni * 16) * 1028 + 1024 + m];
  }
#pragma unroll
  for (int mi = 0; mi < 4; ++mi)
#pragma unroll
    for (int j = 0; j < 4; ++j) {
      const int r = y * 128 + rb + mi * 16 + j;
      f32x4_t psv = *(const f32x4_t*)(ps + (size_t)r * 4);
#pragma unroll
      for (int ni = 0; ni < 4; ++ni) {
        float val = acc[mi][ni][j] + bv[ni]
                  + psv[0] * wt[ni][0] + psv[1] * wt[ni][1]
                  + psv[2] * wt[ni][2] + psv[3] * wt[ni][3];
        obuf[(size_t)r * 256 + cb + ni * 16] = val;
      }
    }
}

// ---- prep: convert intra weights f32 -> bf16 ----
__device__ __forceinline__ void cp8(bf16* d, const float* s) {
  f32x4_t x0 = *(const f32x4_t*)s;
  f32x4_t x1 = *(const f32x4_t*)(s + 4);
  *(bf16x8_t*)d = cvt8(x0, x1);
}
__global__ __launch_bounds__(256) void prep_kernel(
    const float* __restrict__ w0, const float* __restrict__ w1s,
    const float* __restrict__ w2, const float* __restrict__ w3,
    bf16* __restrict__ o0, bf16* __restrict__ o1,
    bf16* __restrict__ o2, bf16* __restrict__ o3) {
  const int t = blockIdx.x * 256 + threadIdx.x;
  if (t < 65536)       { size_t i = (size_t)t * 8;            cp8(o0 + i, w0 + i); }
  else if (t < 114688) { size_t i = (size_t)(t - 65536) * 8;  cp8(o1 + i, w1s + i); }
  else if (t < 147456) { size_t i = (size_t)(t - 114688) * 8; cp8(o2 + i, w2 + i); }
  else                 { size_t i = (size_t)(t - 147456) * 8; cp8(o3 + i, w3 + i); }
}

// ---- attention: 4x4 scores (k=q per source bug), softmax(-UW*(vi+vj)), z=s@v ----
__global__ __launch_bounds__(256)
void attn_kernel(const bf16* __restrict__ qv, const float* __restrict__ pvars,
                 bf16* __restrict__ z) {
  const int b    = blockIdx.x * 4 + (threadIdx.x >> 6);
  const int lane = threadIdx.x & 63;
  float qf[4][4], vf[4][4];
#pragma unroll
  for (int i = 0; i < 4; ++i) {
    const bf16* row = qv + ((size_t)b * 4 + i) * 512;
    bf16x4_t qq = *(const bf16x4_t*)(row + lane * 4);
    bf16x4_t vv = *(const bf16x4_t*)(row + 256 + lane * 4);
#pragma unroll
    for (int c = 0; c < 4; ++c) { qf[i][c] = (float)qq[c]; vf[i][c] = (float)vv[c]; }
  }
  float s[4][4];
#pragma unroll
  for (int i = 0; i < 4; ++i)
#pragma unroll
    for (int j = 0; j < 4; ++j)
      s[i][j] = qf[i][0] * qf[j][0] + qf[i][1] * qf[j][1] + qf[i][2] * qf[j][2] + qf[i][3] * qf[j][3];
#pragma unroll
  for (int off = 1; off < 64; off <<= 1)
#pragma unroll
    for (int i = 0; i < 4; ++i)
#pragma unroll
      for (int j = 0; j < 4; ++j) s[i][j] += __shfl_xor(s[i][j], off);

  float var4[4];
#pragma unroll
  for (int m = 0; m < 4; ++m) var4[m] = pvars[(size_t)b * 4 + m];
  float w[4][4];
#pragma unroll
  for (int i = 0; i < 4; ++i) {
    float t[4]; float mx = -1e30f;
#pragma unroll
    for (int j = 0; j < 4; ++j) { t[j] = s[i][j] - 0.1f * (var4[i] + var4[j]); mx = fmaxf(mx, t[j]); }
    float sum = 0.f;
#pragma unroll
    for (int j = 0; j < 4; ++j) { t[j] = expf(t[j] - mx); sum += t[j]; }
    const float is = 1.f / sum;
#pragma unroll
    for (int j = 0; j < 4; ++j) w[i][j] = t[j] * is;
  }
#pragma unroll
  for (int i = 0; i < 4; ++i) {
    bf16x4_t zo;
#pragma unroll
    for (int c = 0; c < 4; ++c) {
      float zf = w[i][0] * vf[0][c] + w[i][1] * vf[1][c] + w[i][2] * vf[2][c] + w[i][3] * vf[3][c];
      zo[c] = (bf16)zf;
    }
    *(bf16x4_t*)(z + ((size_t)b * 4 + i) * 256 + lane * 4) = zo;
  }
}

// ---- final fc (256 -> 1) + sigmoid ----
__global__ __launch_bounds__(256)
void fc_kernel(const float* __restrict__ o, const float* __restrict__ wfc,
               const float* __restrict__ bfc, float* __restrict__ out) {
  const int b    = blockIdx.x * 4 + (threadIdx.x >> 6);
  const int lane = threadIdx.x & 63;
  f32x4_t ov = *(const f32x4_t*)(o + (size_t)b * 256 + lane * 4);
  f32x4_t wv = *(const f32x4_t*)(wfc + lane * 4);
  float p = ov[0] * wv[0] + ov[1] * wv[1] + ov[2] * wv[2] + ov[3] * wv[3];
#pragma unroll
  for (int off = 1; off < 64; off <<= 1) p += __shfl_xor(p, off);
  if (lane == 0) {
    const float lg = p + bfc[0];
    out[b] = 1.f / (1.f + expf(-lg));
  }
}

extern "C" void kernel_launch(void* const* d_in, const int* in_sizes, int n_in,
                              void* d_out, int out_size, void* d_ws, size_t ws_size,
                              hipStream_t stream) {
  (void)in_sizes; (void)n_in; (void)out_size; (void)ws_size;
  const float* feat[4] = {(const float*)d_in[0], (const float*)d_in[3],
                          (const float*)d_in[6], (const float*)d_in[9]};
  const float* Wi[4]   = {(const float*)d_in[1], (const float*)d_in[4],
                          (const float*)d_in[7], (const float*)d_in[10]};
  const float* bi[4]   = {(const float*)d_in[2], (const float*)d_in[5],
                          (const float*)d_in[8], (const float*)d_in[11]};
  const float* ps  = (const float*)d_in[12];
  const float* pv  = (const float*)d_in[13];
  const float* lng = (const float*)d_in[14];
  const float* lnb = (const float*)d_in[15];
  const float* Wq  = (const float*)d_in[16];
  const float* bq  = (const float*)d_in[17];
  const float* Wv  = (const float*)d_in[20];
  const float* bvp = (const float*)d_in[21];
  const float* W1  = (const float*)d_in[22];
  const float* b1  = (const float*)d_in[23];
  const float* Wfc = (const float*)d_in[24];
  const float* bfc = (const float*)d_in[25];

  char* ws = (char*)d_ws;
  const size_t MB = 1024 * 1024;
  bf16*  hbuf  = (bf16*)ws;                        // [0,64M): H (intra_ln out)
  bf16*  zbuf  = (bf16*)ws;                        // [0,32M): z (after stage C)
  float* obuf  = (float*)(ws + 32 * MB);           // [32M,48M)
  bf16*  wb0   = (bf16*)(ws + 64 * MB);            // intra only
  bf16*  wb1   = (bf16*)(ws + 65 * MB);
  bf16*  wb2   = (bf16*)(ws + 65 * MB + 786432);
  bf16*  wb3   = (bf16*)(ws + 66 * MB + 262144);
  bf16*  qvout = (bf16*)(ws + 64 * MB);            // stage C (clobbers wb*)

  hipLaunchKernelGGL(prep_kernel, dim3(736), dim3(256), 0, stream,
                     Wi[0], Wi[1], Wi[2], Wi[3], wb0, wb1, wb2, wb3);
  hipLaunchKernelGGL(intra_ln_kernel, dim3(512), dim3(1024), 0, stream,
                     feat[0], feat[1], feat[2], feat[3],
                     wb0, wb1, wb2, wb3, bi[0], bi[1], bi[2], bi[3],
                     lng, lnb, hbuf);
  hipLaunchKernelGGL(qv_kernel, dim3(2048), dim3(256), 0, stream,
                     hbuf, Wq, Wv, bq, bvp, qvout);
  hipLaunchKernelGGL(attn_kernel, dim3(16384 / 4), dim3(256), 0, stream, qvout, pv, zbuf);
  hipLaunchKernelGGL(w1_kernel, dim3(256), dim3(256), 0, stream, zbuf, W1, b1, ps, obuf);
  hipLaunchKernelGGL(fc_kernel, dim3(16384 / 4), dim3(256), 0, stream, obuf, Wfc, bfc, (float*)d_out);
}

// Round 19
// 227.834 us; speedup vs baseline: 1.1022x; 1.0891x over previous
//
#include <hip/hip_runtime.h>
#include <hip/hip_bf16.h>

// ---------------------------------------------------------------------------
// HybridFusionNetworkWithUncertainty — MI355X (gfx950), round 19
// r18 failed: wqv/w1b at [48M,49M) sit inside H [0,64M) -> clobbered by
// intra_ln's H write (r3 bug class). During stage C, H(64M)+qvout(64M) fill
// the entire 128MiB ws: no safe home exists for bf16 weight copies that must
// survive prep->stageC. Revert to the r14-proven configuration (best pass:
// 228.73us, absmax 3.9e-3):
//  - intra_ln: 128x512 tile, 8 waves, B bf16 3x32K gl_lds (2-ahead) +
//    A f32 reg-staged (1-ahead) -> bf16 2x8K, vmcnt(4) counted FIFO,
//    fused LayerNorm epilogue, balanced z^2-paired XCD mapping. 112KB LDS.
//  - qv/w1: mixed core_deep3_0 (A bf16 8K + B f32 16K, 3-deep, vmcnt 12/6/0).
//  - attn/fc/prep unchanged.
// ws: H [0,64M); zbuf [0,32M); obuf [32M,48M); wb0-3 @64M (intra only);
//     qvout [64M,128M) (stage C clobbers wb*).
// ---------------------------------------------------------------------------

typedef __bf16 bf16;
typedef __bf16 bf16x4_t __attribute__((ext_vector_type(4)));
typedef __bf16 bf16x8_t __attribute__((ext_vector_type(8)));
typedef float  f32x4_t  __attribute__((ext_vector_type(4)));

__device__ __forceinline__ bf16x8_t cvt8(f32x4_t a, f32x4_t b) {
  bf16x8_t r;
  r[0] = (bf16)a[0]; r[1] = (bf16)a[1]; r[2] = (bf16)a[2]; r[3] = (bf16)a[3];
  r[4] = (bf16)b[0]; r[5] = (bf16)b[1]; r[6] = (bf16)b[2]; r[7] = (bf16)b[3];
  return r;
}

__device__ __forceinline__ void gl_lds16(const void* g, void* l) {
  __builtin_amdgcn_global_load_lds(
      (const __attribute__((address_space(1))) void*)g,
      (__attribute__((address_space(3))) void*)l, 16, 0, 0);
}

#define SBAR()   __builtin_amdgcn_s_barrier()
#define SCHED0() __builtin_amdgcn_sched_barrier(0)

// bf16 tile rows of 32 bf16 (64B): chunk c of row r at c^((r>>1)&3)
__device__ __forceinline__ bf16x8_t frag_b16(const bf16* Ts, int row, int c0) {
  const int byte = row * 64 + ((c0 ^ ((row >> 1) & 3)) << 4);
  return *(const bf16x8_t*)((const char*)Ts + byte);
}
// f32 tile rows of 32 f32 (128B): 16B chunk q of row r at q^(r&7)
__device__ __forceinline__ bf16x8_t frag_f32(const float* Ts, int row, int g) {
  const int p0 = (2 * g)     ^ (row & 7);
  const int p1 = (2 * g + 1) ^ (row & 7);
  f32x4_t lo = *(const f32x4_t*)((const char*)Ts + row * 128 + (p0 << 4));
  f32x4_t hi = *(const f32x4_t*)((const char*)Ts + row * 128 + (p1 << 4));
  return cvt8(lo, hi);
}

// ---- 512-thread staging: bf16 [512][32] (32KB), 4 gl_lds/thread ----
__device__ __forceinline__ void stage_b512x32(const bf16* __restrict__ src, int ld,
                                              int k0, bf16* lds) {
  const int l = threadIdx.x & 63;
  const int w = threadIdx.x >> 6;
#pragma unroll
  for (int j = 0; j < 4; ++j) {
    const int rb = w * 64 + j * 16;
    const int r  = rb + (l >> 2);
    const int sc = (l & 3) ^ ((r >> 1) & 3);
    gl_lds16(src + (size_t)r * ld + k0 + sc * 8, (char*)lds + rb * 64);
  }
}

// ---- stage A (fused): intra GEMM 128x512 + relu + LN -> H ----
__global__ __launch_bounds__(512) void intra_ln_kernel(
    const float* __restrict__ f0, const float* __restrict__ f1,
    const float* __restrict__ f2, const float* __restrict__ f3,
    const bf16* __restrict__ wb0, const bf16* __restrict__ wb1,
    const bf16* __restrict__ wb2, const bf16* __restrict__ wb3,
    const float* __restrict__ bb0, const float* __restrict__ bb1,
    const float* __restrict__ bb2, const float* __restrict__ bb3,
    const float* __restrict__ lng, const float* __restrict__ lnb,
    bf16* __restrict__ Hout) {
  __shared__ __align__(16) char lds[114688];       // B 3x32K + A 2x8K = 112KB

  const int bid  = blockIdx.x;                     // 512 blocks
  const int p    = bid & 255, half = bid >> 8;
  const int px   = (p & 7) * 32 + (p >> 3);        // XCD-chunked bijection
  int z = px & 3, y = px >> 2;                     // y 0..63
  if (half) { z ^= 2; y += 64; }                   // complementary K pairing
  const float* fp; const bf16* wp; const float* bp; int K;
  switch (z) {
    case 0:  fp = f0; wp = wb0; bp = bb0; K = 1024; break;
    case 1:  fp = f1; wp = wb1; bp = bb1; K = 768;  break;
    case 2:  fp = f2; wp = wb2; bp = bb2; K = 512;  break;
    default: fp = f3; wp = wb3; bp = bb3; K = 640;  break;
  }
  const float* A = fp + (size_t)(y * 128) * K;
  const bf16*  B = wp;
  const int tid = threadIdx.x;
  const int lane = tid & 63;
  const int wid  = tid >> 6;                       // 0..7
  const int wm = wid >> 2, wn = wid & 3;           // wave = 64 rows x 128 cols
  const int fr = lane & 15, g = lane >> 4;

  const int srow = tid >> 2, sq = tid & 3;         // A: 4 thr/row, 8 f32 each
  const float* Af = A + (size_t)srow * K + sq * 8;
  const int abyte = srow * 64 + ((sq ^ ((srow >> 1) & 3)) << 4);

  f32x4_t acc[4][8];
#pragma unroll
  for (int i = 0; i < 4; ++i)
#pragma unroll
    for (int j = 0; j < 8; ++j) acc[i][j] = (f32x4_t){0.f, 0.f, 0.f, 0.f};

  const int nt = K >> 5;                           // 16..32, always even

  stage_b512x32(B, K, 0, (bf16*)(lds));
  f32x4_t aA0 = *(const f32x4_t*)(Af + 0);
  f32x4_t aA1 = *(const f32x4_t*)(Af + 4);
  stage_b512x32(B, K, 32, (bf16*)(lds + 32768));
  f32x4_t aB0, aB1;

  int bcur = 0;
#define INTRA_ITER(T, C0, C1, N0, N1)                                         \
  {                                                                           \
    const int t_ = (T);                                                       \
    if (t_ < nt - 1) asm volatile("s_waitcnt vmcnt(4)" ::: "memory");         \
    else             asm volatile("s_waitcnt vmcnt(0)" ::: "memory");         \
    *(bf16x8_t*)(lds + 98304 + (t_ & 1) * 8192 + abyte) = cvt8(C0, C1);       \
    asm volatile("s_waitcnt lgkmcnt(0)" ::: "memory");                        \
    SBAR(); SCHED0();                                                         \
    if (t_ + 1 < nt) {                                                        \
      N0 = *(const f32x4_t*)(Af + (t_ + 1) * 32);                             \
      N1 = *(const f32x4_t*)(Af + (t_ + 1) * 32 + 4);                         \
    }                                                                         \
    SCHED0();                                                                 \
    __builtin_amdgcn_s_setprio(1);                                            \
    {                                                                         \
      const bf16* Ac = (const bf16*)(lds + 98304 + (t_ & 1) * 8192);          \
      const bf16* Bc = (const bf16*)(lds + bcur * 32768);                     \
      bf16x8_t ar[4], br[8];                                                  \
      _Pragma("unroll")                                                       \
      for (int mi = 0; mi < 4; ++mi) ar[mi] = frag_b16(Ac, wm * 64 + mi * 16 + fr, g); \
      _Pragma("unroll")                                                       \
      for (int ni = 0; ni < 8; ++ni) br[ni] = frag_b16(Bc, wn * 128 + ni * 16 + fr, g); \
      _Pragma("unroll")                                                       \
      for (int mi = 0; mi < 4; ++mi)                                          \
        _Pragma("unroll")                                                     \
        for (int ni = 0; ni < 8; ++ni)                                        \
          acc[mi][ni] = __builtin_amdgcn_mfma_f32_16x16x32_bf16(ar[mi], br[ni], acc[mi][ni], 0, 0, 0); \
    }                                                                         \
    __builtin_amdgcn_s_setprio(0);                                            \
    SCHED0(); SBAR();                                                         \
    const int bn_ = (bcur == 2) ? 0 : bcur + 1;                               \
    const int b2_ = (bn_ == 2) ? 0 : bn_ + 1;                                 \
    if (t_ + 2 < nt) stage_b512x32(B, K, (t_ + 2) * 32, (bf16*)(lds + b2_ * 32768)); \
    bcur = bn_;                                                               \
  }

  for (int t = 0; t < nt; t += 2) {
    INTRA_ITER(t,     aA0, aA1, aB0, aB1)
    INTRA_ITER(t + 1, aB0, aB1, aA0, aA1)
  }
#undef INTRA_ITER

  // ---- fused LayerNorm epilogue ----
  float* part  = (float*)lds;                      // [8][64][2] = 4KB
  float* muinv = (float*)(lds + 4096);             // [128][2]   = 1KB
  float bv8[8];
#pragma unroll
  for (int ni = 0; ni < 8; ++ni) bv8[ni] = bp[wn * 128 + ni * 16 + fr];
#pragma unroll
  for (int mi = 0; mi < 4; ++mi)
#pragma unroll
    for (int j = 0; j < 4; ++j) {
      float s = 0.f, s2 = 0.f;
#pragma unroll
      for (int ni = 0; ni < 8; ++ni) {
        float v = fmaxf(acc[mi][ni][j] + bv8[ni], 0.f);
        s += v; s2 += v * v;
      }
#pragma unroll
      for (int off = 1; off < 16; off <<= 1) {
        s += __shfl_xor(s, off); s2 += __shfl_xor(s2, off);
      }
      if (fr == 0) {
        const int rl = mi * 16 + 4 * g + j;        // 0..63
        part[(wid * 64 + rl) * 2]     = s;
        part[(wid * 64 + rl) * 2 + 1] = s2;
      }
    }
  __syncthreads();
  if (tid < 128) {
    const int wmt = tid >> 6, rl = tid & 63;
    float s = 0.f, s2 = 0.f;
#pragma unroll
    for (int q = 0; q < 4; ++q) {
      s  += part[((wmt * 4 + q) * 64 + rl) * 2];
      s2 += part[((wmt * 4 + q) * 64 + rl) * 2 + 1];
    }
    const float mu  = s * (1.f / 512.f);
    const float var = s2 * (1.f / 512.f) - mu * mu;
    muinv[tid * 2]     = mu;
    muinv[tid * 2 + 1] = rsqrtf(var + 1e-5f);
  }
  __syncthreads();
  float gg[8], be[8];
#pragma unroll
  for (int ni = 0; ni < 8; ++ni) {
    const int col = wn * 128 + ni * 16 + fr;
    gg[ni] = lng[col]; be[ni] = lnb[col];
  }
#pragma unroll
  for (int mi = 0; mi < 4; ++mi)
#pragma unroll
    for (int j = 0; j < 4; ++j) {
      const int row = wm * 64 + mi * 16 + 4 * g + j;
      const float mu  = muinv[row * 2];
      const float inv = muinv[row * 2 + 1];
      bf16* hp = Hout + (size_t)(y * 128 + row) * 2048 + z * 512;
#pragma unroll
      for (int ni = 0; ni < 8; ++ni) {
        float v = fmaxf(acc[mi][ni][j] + bv8[ni], 0.f);
        hp[wn * 128 + ni * 16 + fr] = (bf16)((v - mu) * inv * gg[ni] + be[ni]);
      }
    }
}

// ================= 256-thread helpers (qv/w1) =================
__device__ __forceinline__ void stage_b16(const bf16* __restrict__ src, int ld,
                                          int k0, bf16* lds) {
  const int l = threadIdx.x & 63;
  const int w = threadIdx.x >> 6;
#pragma unroll
  for (int j = 0; j < 2; ++j) {
    const int rb = w * 32 + j * 16;
    const int r  = rb + (l >> 2);
    const int sc = (l & 3) ^ ((r >> 1) & 3);
    gl_lds16(src + (size_t)r * ld + k0 + sc * 8, (char*)lds + rb * 64);
  }
}
__device__ __forceinline__ void stage_f32(const float* __restrict__ src, int ld,
                                          int k0, float* lds) {
  const int l = threadIdx.x & 63;
  const int w = threadIdx.x >> 6;
#pragma unroll
  for (int j = 0; j < 4; ++j) {
    const int rb = w * 32 + j * 8;
    const int r  = rb + (l >> 3);
    const int q  = (l & 7) ^ (r & 7);
    gl_lds16(src + (size_t)r * ld + k0 + q * 4, (char*)lds + rb * 128);
  }
}
__device__ __forceinline__ void mfma_deep0(const char* buf, f32x4_t acc[4][4]) {
  const int lane = threadIdx.x & 63;
  const int wid  = threadIdx.x >> 6;
  const int wm = wid >> 1, wn = wid & 1;
  const int fr = lane & 15, g = lane >> 4;
  const bf16*  Ab = (const bf16*)buf;
  const float* Bf = (const float*)(buf + 8192);
  bf16x8_t ar[4], br[4];
#pragma unroll
  for (int mi = 0; mi < 4; ++mi) ar[mi] = frag_b16(Ab, wm * 64 + mi * 16 + fr, g);
#pragma unroll
  for (int ni = 0; ni < 4; ++ni) br[ni] = frag_f32(Bf, wn * 64 + ni * 16 + fr, g);
#pragma unroll
  for (int mi = 0; mi < 4; ++mi)
#pragma unroll
    for (int ni = 0; ni < 4; ++ni)
      acc[mi][ni] = __builtin_amdgcn_mfma_f32_16x16x32_bf16(ar[mi], br[ni], acc[mi][ni], 0, 0, 0);
}
__device__ __forceinline__ void core_deep3_0(const void* A, int lda, const void* B,
                                             int ldb, int K, char* lds,
                                             f32x4_t acc[4][4]) {
  const int nt = K >> 5;
  auto stage = [&](int t, char* buf) {
    stage_b16((const bf16*)A, lda, t * 32, (bf16*)buf);
    stage_f32((const float*)B, ldb, t * 32, (float*)(buf + 8192));
  };
  stage(0, lds); stage(1, lds + 24576); stage(2, lds + 49152);
  int bsel = 0;
  for (int t = 0; t < nt; ++t) {
    const int ahead = nt - 1 - t;
    if (ahead >= 2)      asm volatile("s_waitcnt vmcnt(12)" ::: "memory");
    else if (ahead == 1) asm volatile("s_waitcnt vmcnt(6)"  ::: "memory");
    else                 asm volatile("s_waitcnt vmcnt(0)"  ::: "memory");
    SBAR(); SCHED0();
    __builtin_amdgcn_s_setprio(1);
    mfma_deep0(lds + bsel * 24576, acc);
    __builtin_amdgcn_s_setprio(0);
    SCHED0(); SBAR();
    if (t + 3 < nt) stage(t + 3, lds + bsel * 24576);
    bsel = (bsel == 2) ? 0 : bsel + 1;
  }
}
template<int RELU>
__device__ __forceinline__ void epi_bf16(f32x4_t acc[4][4], bf16* __restrict__ C, int ldc,
                                         const float* __restrict__ bias) {
  const int lane = threadIdx.x & 63;
  const int wid  = threadIdx.x >> 6;
  const int wm = wid >> 1, wn = wid & 1;
  const int fr = lane & 15;
  const int rb = wm * 64 + 4 * (lane >> 4);
  const int cb = wn * 64 + fr;
  float bv[4];
#pragma unroll
  for (int ni = 0; ni < 4; ++ni) bv[ni] = bias[cb + ni * 16];
#pragma unroll
  for (int mi = 0; mi < 4; ++mi)
#pragma unroll
    for (int j = 0; j < 4; ++j)
#pragma unroll
      for (int ni = 0; ni < 4; ++ni) {
        float val = acc[mi][ni][j] + bv[ni];
        if (RELU) val = fmaxf(val, 0.f);
        C[(size_t)(rb + mi * 16 + j) * ldc + cb + ni * 16] = (bf16)val;
      }
}

// ---- stage C: fused q||v projection (65536 x 256 each, K=512) ----
__global__ __launch_bounds__(256) void qv_kernel(
    const bf16* __restrict__ H, const float* __restrict__ Wq,
    const float* __restrict__ Wv, const float* __restrict__ bq,
    const float* __restrict__ bv, bf16* __restrict__ qvout) {
  __shared__ __align__(16) char lds[73728];
  const int bid = blockIdx.x;                     // 2048 blocks
  const int lid = (bid & 7) * 256 + (bid >> 3);
  const int x = lid & 3, y = lid >> 2;            // y: 0..511
  const float* Wsrc = (x < 2) ? Wq : Wv;
  f32x4_t acc[4][4];
#pragma unroll
  for (int i = 0; i < 4; ++i)
#pragma unroll
    for (int j = 0; j < 4; ++j) acc[i][j] = (f32x4_t){0.f, 0.f, 0.f, 0.f};
  core_deep3_0(H + (size_t)(y * 128) * 512, 512,
               Wsrc + (size_t)((x & 1) * 128) * 512, 512, 512, lds, acc);
  const float* bias = (x < 2) ? bq + x * 128 : bv + (x - 2) * 128;
  epi_bf16<0>(acc, qvout + (size_t)(y * 128) * 512 + x * 128, 512, bias);
}

// ---- stage E: W1 GEMM (K=1024, ldw=1028) + pred_scores rank-4 fixup ----
__global__ __launch_bounds__(256) void w1_kernel(
    const bf16* __restrict__ zb, const float* __restrict__ W1,
    const float* __restrict__ b1, const float* __restrict__ ps,
    float* __restrict__ obuf) {
  __shared__ __align__(16) char lds[73728];
  const int bid = blockIdx.x;                     // 256 blocks
  const int lid = (bid & 7) * 32 + (bid >> 3);
  const int x = lid & 1, y = lid >> 1;            // y: 0..127
  f32x4_t acc[4][4];
#pragma unroll
  for (int i = 0; i < 4; ++i)
#pragma unroll
    for (int j = 0; j < 4; ++j) acc[i][j] = (f32x4_t){0.f, 0.f, 0.f, 0.f};
  core_deep3_0(zb + (size_t)(y * 128) * 1024, 1024,
               W1 + (size_t)(x * 128) * 1028, 1028, 1024, lds, acc);

  const int lane = threadIdx.x & 63;
  const int wid  = threadIdx.x >> 6;
  const int wm = wid >> 1, wn = wid & 1;
  const int fr = lane & 15;
  const int rb = wm * 64 + 4 * (lane >> 4);
  const int cb = x * 128 + wn * 64 + fr;
  float bv[4], wt[4][4];
#pragma unroll
  for (int ni = 0; ni < 4; ++ni) {
    bv[ni] = b1[cb + ni * 16];
#pragma unroll
    for (int m = 0; m < 4; ++m) wt[ni][m] = W1[(size_t)(cb + ni * 16) * 1028 + 1024 + m];
  }
#pragma unroll
  for (int mi = 0; mi < 4; ++mi)
#pragma unroll
    for (int j = 0; j < 4; ++j) {
      const int r = y * 128 + rb + mi * 16 + j;
      f32x4_t psv = *(const f32x4_t*)(ps + (size_t)r * 4);
#pragma unroll
      for (int ni = 0; ni < 4; ++ni) {
        float val = acc[mi][ni][j] + bv[ni]
                  + psv[0] * wt[ni][0] + psv[1] * wt[ni][1]
                  + psv[2] * wt[ni][2] + psv[3] * wt[ni][3];
        obuf[(size_t)r * 256 + cb + ni * 16] = val;
      }
    }
}

// ---- prep: convert intra weights f32 -> bf16 ----
__device__ __forceinline__ void cp8(bf16* d, const float* s) {
  f32x4_t x0 = *(const f32x4_t*)s;
  f32x4_t x1 = *(const f32x4_t*)(s + 4);
  *(bf16x8_t*)d = cvt8(x0, x1);
}
__global__ __launch_bounds__(256) void prep_kernel(
    const float* __restrict__ w0, const float* __restrict__ w1s,
    const float* __restrict__ w2, const float* __restrict__ w3,
    bf16* __restrict__ o0, bf16* __restrict__ o1,
    bf16* __restrict__ o2, bf16* __restrict__ o3) {
  const int t = blockIdx.x * 256 + threadIdx.x;
  if (t < 65536)       { size_t i = (size_t)t * 8;            cp8(o0 + i, w0 + i); }
  else if (t < 114688) { size_t i = (size_t)(t - 65536) * 8;  cp8(o1 + i, w1s + i); }
  else if (t < 147456) { size_t i = (size_t)(t - 114688) * 8; cp8(o2 + i, w2 + i); }
  else                 { size_t i = (size_t)(t - 147456) * 8; cp8(o3 + i, w3 + i); }
}

// ---- attention: 4x4 scores (k=q per source bug), softmax(-UW*(vi+vj)), z=s@v ----
__global__ __launch_bounds__(256)
void attn_kernel(const bf16* __restrict__ qv, const float* __restrict__ pvars,
                 bf16* __restrict__ z) {
  const int b    = blockIdx.x * 4 + (threadIdx.x >> 6);
  const int lane = threadIdx.x & 63;
  float qf[4][4], vf[4][4];
#pragma unroll
  for (int i = 0; i < 4; ++i) {
    const bf16* row = qv + ((size_t)b * 4 + i) * 512;
    bf16x4_t qq = *(const bf16x4_t*)(row + lane * 4);
    bf16x4_t vv = *(const bf16x4_t*)(row + 256 + lane * 4);
#pragma unroll
    for (int c = 0; c < 4; ++c) { qf[i][c] = (float)qq[c]; vf[i][c] = (float)vv[c]; }
  }
  float s[4][4];
#pragma unroll
  for (int i = 0; i < 4; ++i)
#pragma unroll
    for (int j = 0; j < 4; ++j)
      s[i][j] = qf[i][0] * qf[j][0] + qf[i][1] * qf[j][1] + qf[i][2] * qf[j][2] + qf[i][3] * qf[j][3];
#pragma unroll
  for (int off = 1; off < 64; off <<= 1)
#pragma unroll
    for (int i = 0; i < 4; ++i)
#pragma unroll
      for (int j = 0; j < 4; ++j) s[i][j] += __shfl_xor(s[i][j], off);

  float var4[4];
#pragma unroll
  for (int m = 0; m < 4; ++m) var4[m] = pvars[(size_t)b * 4 + m];
  float w[4][4];
#pragma unroll
  for (int i = 0; i < 4; ++i) {
    float t[4]; float mx = -1e30f;
#pragma unroll
    for (int j = 0; j < 4; ++j) { t[j] = s[i][j] - 0.1f * (var4[i] + var4[j]); mx = fmaxf(mx, t[j]); }
    float sum = 0.f;
#pragma unroll
    for (int j = 0; j < 4; ++j) { t[j] = expf(t[j] - mx); sum += t[j]; }
    const float is = 1.f / sum;
#pragma unroll
    for (int j = 0; j < 4; ++j) w[i][j] = t[j] * is;
  }
#pragma unroll
  for (int i = 0; i < 4; ++i) {
    bf16x4_t zo;
#pragma unroll
    for (int c = 0; c < 4; ++c) {
      float zf = w[i][0] * vf[0][c] + w[i][1] * vf[1][c] + w[i][2] * vf[2][c] + w[i][3] * vf[3][c];
      zo[c] = (bf16)zf;
    }
    *(bf16x4_t*)(z + ((size_t)b * 4 + i) * 256 + lane * 4) = zo;
  }
}

// ---- final fc (256 -> 1) + sigmoid ----
__global__ __launch_bounds__(256)
void fc_kernel(const float* __restrict__ o, const float* __restrict__ wfc,
               const float* __restrict__ bfc, float* __restrict__ out) {
  const int b    = blockIdx.x * 4 + (threadIdx.x >> 6);
  const int lane = threadIdx.x & 63;
  f32x4_t ov = *(const f32x4_t*)(o + (size_t)b * 256 + lane * 4);
  f32x4_t wv = *(const f32x4_t*)(wfc + lane * 4);
  float p = ov[0] * wv[0] + ov[1] * wv[1] + ov[2] * wv[2] + ov[3] * wv[3];
#pragma unroll
  for (int off = 1; off < 64; off <<= 1) p += __shfl_xor(p, off);
  if (lane == 0) {
    const float lg = p + bfc[0];
    out[b] = 1.f / (1.f + expf(-lg));
  }
}

extern "C" void kernel_launch(void* const* d_in, const int* in_sizes, int n_in,
                              void* d_out, int out_size, void* d_ws, size_t ws_size,
                              hipStream_t stream) {
  (void)in_sizes; (void)n_in; (void)out_size; (void)ws_size;
  const float* feat[4] = {(const float*)d_in[0], (const float*)d_in[3],
                          (const float*)d_in[6], (const float*)d_in[9]};
  const float* Wi[4]   = {(const float*)d_in[1], (const float*)d_in[4],
                          (const float*)d_in[7], (const float*)d_in[10]};
  const float* bi[4]   = {(const float*)d_in[2], (const float*)d_in[5],
                          (const float*)d_in[8], (const float*)d_in[11]};
  const float* ps  = (const float*)d_in[12];
  const float* pv  = (const float*)d_in[13];
  const float* lng = (const float*)d_in[14];
  const float* lnb = (const float*)d_in[15];
  const float* Wq  = (const float*)d_in[16];
  const float* bq  = (const float*)d_in[17];
  const float* Wv  = (const float*)d_in[20];
  const float* bvp = (const float*)d_in[21];
  const float* W1  = (const float*)d_in[22];
  const float* b1  = (const float*)d_in[23];
  const float* Wfc = (const float*)d_in[24];
  const float* bfc = (const float*)d_in[25];

  char* ws = (char*)d_ws;
  const size_t MB = 1024 * 1024;
  bf16*  hbuf  = (bf16*)ws;                        // [0,64M): H (intra_ln out)
  bf16*  zbuf  = (bf16*)ws;                        // [0,32M): z (after stage C)
  float* obuf  = (float*)(ws + 32 * MB);           // [32M,48M)
  bf16*  wb0   = (bf16*)(ws + 64 * MB);            // intra only
  bf16*  wb1   = (bf16*)(ws + 65 * MB);
  bf16*  wb2   = (bf16*)(ws + 65 * MB + 786432);
  bf16*  wb3   = (bf16*)(ws + 66 * MB + 262144);
  bf16*  qvout = (bf16*)(ws + 64 * MB);            // stage C (clobbers wb*)

  hipLaunchKernelGGL(prep_kernel, dim3(736), dim3(256), 0, stream,
                     Wi[0], Wi[1], Wi[2], Wi[3], wb0, wb1, wb2, wb3);
  hipLaunchKernelGGL(intra_ln_kernel, dim3(512), dim3(512), 0, stream,
                     feat[0], feat[1], feat[2], feat[3],
                     wb0, wb1, wb2, wb3, bi[0], bi[1], bi[2], bi[3],
                     lng, lnb, hbuf);
  hipLaunchKernelGGL(qv_kernel, dim3(2048), dim3(256), 0, stream,
                     hbuf, Wq, Wv, bq, bvp, qvout);
  hipLaunchKernelGGL(attn_kernel, dim3(16384 / 4), dim3(256), 0, stream, qvout, pv, zbuf);
  hipLaunchKernelGGL(w1_kernel, dim3(256), dim3(256), 0, stream, zbuf, W1, b1, ps, obuf);
  hipLaunchKernelGGL(fc_kernel, dim3(16384 / 4), dim3(256), 0, stream, obuf, Wfc, bfc, (float*)d_out);
}